// Round 5
// baseline (544.432 us; speedup 1.0000x reference)
//
#include <hip/hip_runtime.h>
#include <hip/hip_bf16.h>

#define VOCAB 2048
#define EMBD  256
#define LATD  64
#define TLEN  32
#define BATCH 64
#define NBLK  256

typedef __attribute__((ext_vector_type(8))) short bf16x8;
typedef __attribute__((ext_vector_type(4))) float f32x4;

// ---------------- init: h[parity0]=0, barrier counters=0 ----------------
__global__ void k_init(ushort* __restrict__ h0, unsigned* __restrict__ bar) {
  int i = blockIdx.x * 256 + threadIdx.x;   // grid 512*256 = 131072
  h0[i] = 0;                                 // 64*2048 bf16 (parity 0)
  if (i < TLEN * 9) bar[i] = 0;              // 32 steps x (8 xcd ctrs + master)
}

// ---------- transpose+convert: src[K][8192] f32 -> dst[8192][K] bf16 ----------
__global__ void k_transpose(const float* __restrict__ src,
                            __hip_bfloat16* __restrict__ dst, int K) {
  __shared__ __hip_bfloat16 tile[64][72];
  int k0 = (blockIdx.x >> 7) * 64;
  int n0 = (blockIdx.x & 127) * 64;
  int tid = threadIdx.x;
  {
    int kl = tid >> 2;
    int nq = (tid & 3) << 4;
    const float* s = src + (size_t)(k0 + kl) * 8192 + n0 + nq;
#pragma unroll
    for (int i = 0; i < 4; ++i) {
      float4 v = *reinterpret_cast<const float4*>(s + i * 4);
      tile[nq + i * 4 + 0][kl] = __float2bfloat16(v.x);
      tile[nq + i * 4 + 1][kl] = __float2bfloat16(v.y);
      tile[nq + i * 4 + 2][kl] = __float2bfloat16(v.z);
      tile[nq + i * 4 + 3][kl] = __float2bfloat16(v.w);
    }
  }
  __syncthreads();
  {
    int nl = tid >> 2;
    int kq = (tid & 3) << 4;
    uint4* d = reinterpret_cast<uint4*>(dst + (size_t)(n0 + nl) * K + k0 + kq);
    const uint4* s = reinterpret_cast<const uint4*>(&tile[nl][kq]);
    d[0] = s[0];
    d[1] = s[1];
  }
}

// ---------- gather: xb[t*64+b][256] = bf16(emb[tokens[b][t]]) ----------
__global__ void k_gather(const int* __restrict__ tokens,
                         const float* __restrict__ emb,
                         __hip_bfloat16* __restrict__ xb) {
  int tid = threadIdx.x;
  int row = blockIdx.x * 4 + (tid >> 6);   // 512 blocks -> 2048 rows
  int lane = tid & 63;
  int t = row >> 6, b = row & 63;
  int tok = tokens[b * TLEN + t];
  float4 v = *reinterpret_cast<const float4*>(emb + (size_t)tok * EMBD + lane * 4);
  __hip_bfloat16* d = xb + (size_t)row * EMBD + lane * 4;
  d[0] = __float2bfloat16(v.x);
  d[1] = __float2bfloat16(v.y);
  d[2] = __float2bfloat16(v.z);
  d[3] = __float2bfloat16(v.w);
}

__device__ __forceinline__ void store_agent_u32(unsigned* p, unsigned v) {
  __hip_atomic_store(p, v, __ATOMIC_RELAXED, __HIP_MEMORY_SCOPE_AGENT);
}
__device__ __forceinline__ void store_agent_f32(float* p, float v) {
  __hip_atomic_store(p, v, __ATOMIC_RELAXED, __HIP_MEMORY_SCOPE_AGENT);
}
__device__ __forceinline__ unsigned short bf16_bits(float x) {
  __hip_bfloat16 h = __float2bfloat16(x);
  unsigned short u;
  __builtin_memcpy(&u, &h, 2);
  return u;
}

// Two-level grid barrier. Cross-step data (h/stats) was written with
// agent-scope stores (bypass L2, visible at LLC once vmcnt drains — the
// __syncthreads before arrival drains it). Arrivals: 8 counters of 32
// (blockIdx&7) + master of 8 -> no 256-way same-line serialization.
// Acquire: one cache-wide buffer_inv per block (covers this CU's L1 + L2).
__device__ __forceinline__ void grid_barrier(unsigned* bar, int t, int j) {
  __syncthreads();                       // all waves' stores drained (vmcnt 0)
  if (threadIdx.x == 0) {
    unsigned* xc = bar + t * 9 + (j & 7);
    unsigned* ms = bar + t * 9 + 8;
    unsigned old = __hip_atomic_fetch_add(xc, 1u, __ATOMIC_RELAXED,
                                          __HIP_MEMORY_SCOPE_AGENT);
    if (old == 31u)
      __hip_atomic_fetch_add(ms, 1u, __ATOMIC_RELAXED, __HIP_MEMORY_SCOPE_AGENT);
    while (__hip_atomic_load(ms, __ATOMIC_RELAXED, __HIP_MEMORY_SCOPE_AGENT) < 8u)
      __builtin_amdgcn_s_sleep(2);
    __builtin_amdgcn_fence(__ATOMIC_ACQUIRE, "agent");   // L1+L2 invalidate
  }
  __syncthreads();
}

// ---------------- persistent kernel: all 32 steps ----------------
// 256 blocks x 512 threads, 1 block/CU (all co-resident). Block j owns vocab
// cols v=j*8..j*8+7. 8 waves split K=2304. Wh/Wx fragments live in VGPRs for
// the whole kernel; c in registers; out accumulated in LDS, written at end.
__global__ __launch_bounds__(512, 1) void k_persist(
    const int* __restrict__ tokens,
    const __hip_bfloat16* __restrict__ WhT,   // [8192][2048]
    const __hip_bfloat16* __restrict__ WxT,   // [8192][256]
    const __hip_bfloat16* __restrict__ xb,    // [2048][256] row = t*64+b
    const float* __restrict__ bias,           // [8192]
    __hip_bfloat16* __restrict__ hbuf,        // [2][64][2048]
    float* __restrict__ stats,                // [2][3][64][256]
    float* __restrict__ out,                  // [64][32][64]
    unsigned* __restrict__ bar) {             // [32*9]
  const int tid = threadIdx.x;
  const int lane = tid & 63;
  const int wid = tid >> 6;                  // 0..7
  const int j = blockIdx.x;

  __shared__ float racc[8][4][2][4][64];   // [wid][mf][nf][r][lane] 64KB
  __shared__ float sval[TLEN];

  const int rr = lane & 15;
  const int kg = lane >> 4;                 // 0..3 (K groups of 8)
  const int gcol0 = ((rr >> 3) << 11) + (j << 3) + (rr & 7);          // cols 0..15
  const int gcol1 = (((16 + rr) >> 3) << 11) + (j << 3) + (rr & 7);   // cols 16..31

  // ---- preload B fragments into registers (immune to L2 invalidates) ----
  bf16x8 B0[9], B1[9];
#pragma unroll
  for (int it = 0; it < 8; ++it) {
    int kb = (wid + 8 * (it >> 1)) * 64 + (it & 1) * 32 + kg * 8;
    B0[it] = *(const bf16x8*)(WhT + (size_t)gcol0 * VOCAB + kb);
    B1[it] = *(const bf16x8*)(WhT + (size_t)gcol1 * VOCAB + kb);
  }
  {
    int kbx = wid * 32 + kg * 8;
    B0[8] = *(const bf16x8*)(WxT + (size_t)gcol0 * EMBD + kbx);
    B1[8] = *(const bf16x8*)(WxT + (size_t)gcol1 * EMBD + kbx);
  }

  // ---- epilogue constants; c in registers ----
  const int m = wid >> 1;                  // fragment 0..3
  const int half = wid & 1;                // r in {2*half, 2*half+1}
  const int s_ = (lane >> 3) & 1;
  const int vc = lane & 7;
  const int v = (j << 3) + vc;
  const float bias0 = bias[s_ * 2048 + v];        // frag0 gate: i (s=0) / f (s=1)
  const float bias1 = bias[(2 + s_) * 2048 + v];  // frag1 gate: g (s=0) / o (s=1)
  const int row0 = m * 16 + kg * 4 + half * 2;
  const int row1 = row0 + 1;
  float c_reg[2] = {0.f, 0.f};

  for (int t = 0; t < TLEN; ++t) {
    const int par = t & 1;
    const __hip_bfloat16* hcur = hbuf + par * (BATCH * VOCAB);
    __hip_bfloat16* hnext = hbuf + (par ^ 1) * (BATCH * VOCAB);
    const int tnext = (t + 1 < TLEN) ? t + 1 : TLEN - 1;
    const int tok0 = tokens[row0 * TLEN + tnext];
    const int tok1 = tokens[row1 * TLEN + tnext];

    // ---- bounds value for step t -> sval[t] (wave 0 of blocks j<64) ----
    if (j < BATCH && wid == 0) {
      float val;
      if (t == 0) {
        int tok = tokens[j * TLEN];
        val = 1.5f * (2.f * tok + 1.f) * (1.f / 2048.f);
      } else {
        const float* st = stats + par * 3 * BATCH * NBLK;
        float4 u0 = *reinterpret_cast<const float4*>(st + (0 * BATCH + j) * NBLK + lane * 4);
        float4 u1 = *reinterpret_cast<const float4*>(st + (1 * BATCH + j) * NBLK + lane * 4);
        float4 u2 = *reinterpret_cast<const float4*>(st + (2 * BATCH + j) * NBLK + lane * 4);
        float a0 = u0.x + u0.y + u0.z + u0.w;
        float a1 = u1.x + u1.y + u1.z + u1.w;
        float a2 = u2.x + u2.y + u2.z + u2.w;
#pragma unroll
        for (int mm = 1; mm <= 32; mm <<= 1) {
          a0 += __shfl_xor(a0, mm);
          a1 += __shfl_xor(a1, mm);
          a2 += __shfl_xor(a2, mm);
        }
        val = 1.5f * (2.f * a1 + a2) / a0;
      }
      if (lane == t) sval[t] = val;
    }

    // ---- GEMM: z[64 x 32cols] over K=2304, 8 waves split K, B in regs ----
    f32x4 acc[4][2];
#pragma unroll
    for (int mf = 0; mf < 4; ++mf)
#pragma unroll
      for (int nf = 0; nf < 2; ++nf) acc[mf][nf] = (f32x4){0.f, 0.f, 0.f, 0.f};

    bf16x8 Ar[5][4];
    auto issue = [&](int it) {
      int slot = it % 5;
      if (it < 8) {
        int kb = (wid + 8 * (it >> 1)) * 64 + (it & 1) * 32 + kg * 8;
        const __hip_bfloat16* p = hcur + kb;
        Ar[slot][0] = *(const bf16x8*)(p + (0 * 16 + rr) * VOCAB);
        Ar[slot][1] = *(const bf16x8*)(p + (1 * 16 + rr) * VOCAB);
        Ar[slot][2] = *(const bf16x8*)(p + (2 * 16 + rr) * VOCAB);
        Ar[slot][3] = *(const bf16x8*)(p + (3 * 16 + rr) * VOCAB);
      } else {
        int kbx = wid * 32 + kg * 8;
        const __hip_bfloat16* p = xb + (size_t)t * BATCH * EMBD + kbx;
        Ar[slot][0] = *(const bf16x8*)(p + (0 * 16 + rr) * EMBD);
        Ar[slot][1] = *(const bf16x8*)(p + (1 * 16 + rr) * EMBD);
        Ar[slot][2] = *(const bf16x8*)(p + (2 * 16 + rr) * EMBD);
        Ar[slot][3] = *(const bf16x8*)(p + (3 * 16 + rr) * EMBD);
      }
    };

#pragma unroll
    for (int it = 0; it < 5; ++it) issue(it);
#pragma unroll
    for (int it = 0; it < 9; ++it) {
      const int sl = it % 5;
      acc[0][0] = __builtin_amdgcn_mfma_f32_16x16x32_bf16(Ar[sl][0], B0[it], acc[0][0], 0, 0, 0);
      acc[0][1] = __builtin_amdgcn_mfma_f32_16x16x32_bf16(Ar[sl][0], B1[it], acc[0][1], 0, 0, 0);
      acc[1][0] = __builtin_amdgcn_mfma_f32_16x16x32_bf16(Ar[sl][1], B0[it], acc[1][0], 0, 0, 0);
      acc[1][1] = __builtin_amdgcn_mfma_f32_16x16x32_bf16(Ar[sl][1], B1[it], acc[1][1], 0, 0, 0);
      acc[2][0] = __builtin_amdgcn_mfma_f32_16x16x32_bf16(Ar[sl][2], B0[it], acc[2][0], 0, 0, 0);
      acc[2][1] = __builtin_amdgcn_mfma_f32_16x16x32_bf16(Ar[sl][2], B1[it], acc[2][1], 0, 0, 0);
      acc[3][0] = __builtin_amdgcn_mfma_f32_16x16x32_bf16(Ar[sl][3], B0[it], acc[3][0], 0, 0, 0);
      acc[3][1] = __builtin_amdgcn_mfma_f32_16x16x32_bf16(Ar[sl][3], B1[it], acc[3][1], 0, 0, 0);
      if (it + 5 < 9) issue(it + 5);
    }

    // ---- cross-wave K reduction ----
#pragma unroll
    for (int mf = 0; mf < 4; ++mf)
#pragma unroll
      for (int nf = 0; nf < 2; ++nf)
#pragma unroll
        for (int r = 0; r < 4; ++r) racc[wid][mf][nf][r][lane] = acc[mf][nf][r];
    __syncthreads();

    // ---- epilogue: wave pair (2m,2m+1) finishes fragment m; half splits r ----
    float hn_[2], e_[2], sl_[2], st_[2];
#pragma unroll
    for (int r2 = 0; r2 < 2; ++r2) {
      int r = half * 2 + r2;
      float z0 = bias0, z1 = bias1;
#pragma unroll
      for (int w = 0; w < 8; ++w) {
        z0 += racc[w][m][0][r][lane];
        z1 += racc[w][m][1][r][lane];
      }
      float o0 = __shfl_xor(z0, 8);
      float o1 = __shfl_xor(z1, 8);
      float zi = s_ ? o0 : z0;
      float zf = s_ ? z0 : o0;
      float zg = s_ ? o1 : z1;
      float zo = s_ ? z1 : o1;
      float gi = 1.f / (1.f + __expf(-zi));
      float gf = 1.f / (1.f + __expf(-zf));
      float go = 1.f / (1.f + __expf(-zo));
      float cnew = gf * c_reg[r2] + gi * tanhf(zg);
      float hn = go * tanhf(cnew);
      c_reg[r2] = cnew;
      hn_[r2] = hn;
      float e = __expf(hn);
      int tok = r2 ? tok1 : tok0;
      e_[r2] = e;
      sl_[r2] = (v < tok) ? e : 0.f;
      st_[r2] = (v == tok) ? e : 0.f;
    }

    // h-slice: pack vc pairs -> 4B agent-scope stores (bypass L2 -> LLC)
    {
      unsigned b0 = bf16_bits(hn_[0]), b1 = bf16_bits(hn_[1]);
      unsigned q0 = (unsigned)__shfl_xor((int)b0, 1);
      unsigned q1 = (unsigned)__shfl_xor((int)b1, 1);
      if (!s_ && !(vc & 1)) {
        store_agent_u32((unsigned*)(hnext + row0 * VOCAB + v), b0 | (q0 << 16));
        store_agent_u32((unsigned*)(hnext + row1 * VOCAB + v), b1 | (q1 << 16));
      }
    }
#pragma unroll
    for (int mm = 1; mm <= 4; mm <<= 1)
#pragma unroll
      for (int r2 = 0; r2 < 2; ++r2) {
        e_[r2] += __shfl_xor(e_[r2], mm);
        sl_[r2] += __shfl_xor(sl_[r2], mm);
        st_[r2] += __shfl_xor(st_[r2], mm);
      }
    if (vc == 0 && s_ == 0) {
      float* stn = stats + (par ^ 1) * 3 * BATCH * NBLK;
      store_agent_f32(&stn[(0 * BATCH + row0) * NBLK + j], e_[0]);
      store_agent_f32(&stn[(1 * BATCH + row0) * NBLK + j], sl_[0]);
      store_agent_f32(&stn[(2 * BATCH + row0) * NBLK + j], st_[0]);
      store_agent_f32(&stn[(0 * BATCH + row1) * NBLK + j], e_[1]);
      store_agent_f32(&stn[(1 * BATCH + row1) * NBLK + j], sl_[1]);
      store_agent_f32(&stn[(2 * BATCH + row1) * NBLK + j], st_[1]);
    }

    if (t < TLEN - 1) grid_barrier(bar, t, j);
  }

  // ---- write out[j] once: d<=t' -> sval[d], else 1.5 (initial bounds) ----
  if (j < BATCH) {
    __syncthreads();
    for (int idx = tid; idx < TLEN * LATD; idx += 512) {
      int tp = idx >> 6, d = idx & 63;
      out[j * TLEN * LATD + idx] = (d < TLEN && d <= tp) ? sval[d] : 1.5f;
    }
  }
}

extern "C" void kernel_launch(void* const* d_in, const int* in_sizes, int n_in,
                              void* d_out, int out_size, void* d_ws, size_t ws_size,
                              hipStream_t stream) {
  (void)in_sizes; (void)n_in; (void)out_size; (void)ws_size;
  const int* tokens = (const int*)d_in[0];
  const float* emb  = (const float*)d_in[1];
  const float* Wx   = (const float*)d_in[2];
  const float* Wh   = (const float*)d_in[3];
  const float* bias = (const float*)d_in[4];
  float* out = (float*)d_out;
  char* ws = (char*)d_ws;

  __hip_bfloat16* WhT = (__hip_bfloat16*)(ws);               // 33,554,432 B
  __hip_bfloat16* WxT = (__hip_bfloat16*)(ws + 33554432);    //  4,194,304 B
  __hip_bfloat16* xb  = (__hip_bfloat16*)(ws + 37748736);    //  1,048,576 B
  __hip_bfloat16* hb  = (__hip_bfloat16*)(ws + 38797312);    //    524,288 B
  float* stats        = (float*)(ws + 39321600);             //    393,216 B
  unsigned* bar       = (unsigned*)(ws + 39714816);          //      1,152 B

  k_init<<<512, 256, 0, stream>>>((ushort*)hb, bar);
  k_transpose<<<4096, 256, 0, stream>>>(Wh, WhT, 2048);
  k_transpose<<<512, 256, 0, stream>>>(Wx, WxT, 256);
  k_gather<<<512, 256, 0, stream>>>(tokens, emb, xb);
  k_persist<<<NBLK, 512, 0, stream>>>(tokens, WhT, WxT, xb, bias, hb, stats, out, bar);
}

// Round 6
// 410.636 us; speedup vs baseline: 1.3258x; 1.3258x over previous
//
#include <hip/hip_runtime.h>
#include <hip/hip_bf16.h>

#define VOCAB 2048
#define EMBD  256
#define LATD  64
#define TLEN  32
#define BATCH 64
#define NBLK  256

typedef __attribute__((ext_vector_type(8))) short bf16x8;
typedef __attribute__((ext_vector_type(4))) float f32x4;

// barrier layout (words): arr[(s*8+g)*16] | master[4096+s*16] | rel[4608+g*16]
#define BAR_WORDS 4736

// ---------------- init: h ring slot0 = 0, barrier = 0 ----------------
__global__ void k_init(ushort* __restrict__ h0, unsigned* __restrict__ bar) {
  int i = blockIdx.x * 256 + threadIdx.x;   // grid 512*256 = 131072
  h0[i] = 0;                                 // 64*2048 bf16 (ring slot 0)
  if (i < BAR_WORDS) bar[i] = 0;
}

// ---------- transpose+convert: src[K][8192] f32 -> dst[8192][K] bf16 ----------
__global__ void k_transpose(const float* __restrict__ src,
                            __hip_bfloat16* __restrict__ dst, int K) {
  __shared__ __hip_bfloat16 tile[64][72];
  int k0 = (blockIdx.x >> 7) * 64;
  int n0 = (blockIdx.x & 127) * 64;
  int tid = threadIdx.x;
  {
    int kl = tid >> 2;
    int nq = (tid & 3) << 4;
    const float* s = src + (size_t)(k0 + kl) * 8192 + n0 + nq;
#pragma unroll
    for (int i = 0; i < 4; ++i) {
      float4 v = *reinterpret_cast<const float4*>(s + i * 4);
      tile[nq + i * 4 + 0][kl] = __float2bfloat16(v.x);
      tile[nq + i * 4 + 1][kl] = __float2bfloat16(v.y);
      tile[nq + i * 4 + 2][kl] = __float2bfloat16(v.z);
      tile[nq + i * 4 + 3][kl] = __float2bfloat16(v.w);
    }
  }
  __syncthreads();
  {
    int nl = tid >> 2;
    int kq = (tid & 3) << 4;
    uint4* d = reinterpret_cast<uint4*>(dst + (size_t)(n0 + nl) * K + k0 + kq);
    const uint4* s = reinterpret_cast<const uint4*>(&tile[nl][kq]);
    d[0] = s[0];
    d[1] = s[1];
  }
}

// ---------- gather: xb[t*64+b][256] = bf16(emb[tokens[b][t]]) ----------
__global__ void k_gather(const int* __restrict__ tokens,
                         const float* __restrict__ emb,
                         __hip_bfloat16* __restrict__ xb) {
  int tid = threadIdx.x;
  int row = blockIdx.x * 4 + (tid >> 6);   // 512 blocks -> 2048 rows
  int lane = tid & 63;
  int t = row >> 6, b = row & 63;
  int tok = tokens[b * TLEN + t];
  float4 v = *reinterpret_cast<const float4*>(emb + (size_t)tok * EMBD + lane * 4);
  __hip_bfloat16* d = xb + (size_t)row * EMBD + lane * 4;
  d[0] = __float2bfloat16(v.x);
  d[1] = __float2bfloat16(v.y);
  d[2] = __float2bfloat16(v.z);
  d[3] = __float2bfloat16(v.w);
}

__device__ __forceinline__ void store_agent_u32(unsigned* p, unsigned v) {
  __hip_atomic_store(p, v, __ATOMIC_RELAXED, __HIP_MEMORY_SCOPE_AGENT);
}
__device__ __forceinline__ void store_agent_f32(float* p, float v) {
  __hip_atomic_store(p, v, __ATOMIC_RELAXED, __HIP_MEMORY_SCOPE_AGENT);
}
__device__ __forceinline__ float2 load_agent_f32x2(const float* p) {
  unsigned long long u = __hip_atomic_load((const unsigned long long*)p,
                                           __ATOMIC_RELAXED, __HIP_MEMORY_SCOPE_AGENT);
  float2 f;
  __builtin_memcpy(&f, &u, 8);
  return f;
}
__device__ __forceinline__ unsigned short bf16_bits(float x) {
  __hip_bfloat16 h = __float2bfloat16(x);
  unsigned short u;
  __builtin_memcpy(&u, &h, 2);
  return u;
}

// Grid barrier, no cache invalidation. Cross-step data was written with
// agent-scope stores (bypass L1/L2 -> LLC; proven to reach LLC in round 5);
// readers use either agent loads (stats) or normal cached loads of
// never-before-cached ring lines (h), so no stale copy can exist.
// Arrival: 8 per-XCD counters (32 each) -> master (8). Release: the block
// completing the master writes 8 per-XCD release words (separate lines,
// 32 pollers each) with value t+1 — monotone, no reset needed.
__device__ __forceinline__ void grid_barrier(unsigned* bar, int t, int j) {
  __syncthreads();                       // all waves' stores drained (vmcnt 0)
  if (threadIdx.x == 0) {
    const int g = j & 7;
    unsigned* arr = bar + ((t * 8 + g) << 4);
    unsigned* mst = bar + 4096 + (t << 4);
    unsigned* rel = bar + 4608 + (g << 4);
    unsigned old = __hip_atomic_fetch_add(arr, 1u, __ATOMIC_RELAXED,
                                          __HIP_MEMORY_SCOPE_AGENT);
    if (old == 31u) {
      unsigned mo = __hip_atomic_fetch_add(mst, 1u, __ATOMIC_RELAXED,
                                           __HIP_MEMORY_SCOPE_AGENT);
      if (mo == 7u) {
#pragma unroll
        for (int gg = 0; gg < 8; ++gg)
          store_agent_u32(bar + 4608 + (gg << 4), (unsigned)(t + 1));
      }
    }
    while (__hip_atomic_load(rel, __ATOMIC_RELAXED, __HIP_MEMORY_SCOPE_AGENT) <
           (unsigned)(t + 1))
      __builtin_amdgcn_s_sleep(1);
  }
  __syncthreads();                       // compiler + exec barrier for readers
}

// ---------------- persistent kernel: all 32 steps ----------------
// 256 blocks x 512 threads, 1 block/CU (all co-resident). Block j owns vocab
// cols v=j*8..j*8+7. 8 waves split K=2304. Wh/Wx fragments live in VGPRs for
// the whole kernel; c in registers; h in a 33-slot ring (write-once slots:
// agent stores -> LLC, normal cached reads -> L2-shared per XCD).
__global__ __launch_bounds__(512, 1) void k_persist(
    const int* __restrict__ tokens,
    const __hip_bfloat16* __restrict__ WhT,   // [8192][2048]
    const __hip_bfloat16* __restrict__ WxT,   // [8192][256]
    const __hip_bfloat16* __restrict__ xb,    // [2048][256] row = t*64+b
    const float* __restrict__ bias,           // [8192]
    __hip_bfloat16* __restrict__ hring,       // [33][64][2048]
    float* __restrict__ stats,                // [2][3][64][256]
    float* __restrict__ out,                  // [64][32][64]
    unsigned* __restrict__ bar) {
  const int tid = threadIdx.x;
  const int lane = tid & 63;
  const int wid = tid >> 6;                  // 0..7
  const int j = blockIdx.x;

  __shared__ float racc[8][4][2][4][64];   // [wid][mf][nf][r][lane] 64KB
  __shared__ float sval[TLEN];

  const int rr = lane & 15;
  const int kg = lane >> 4;                 // 0..3 (K groups of 8)
  const int gcol0 = ((rr >> 3) << 11) + (j << 3) + (rr & 7);          // cols 0..15
  const int gcol1 = (((16 + rr) >> 3) << 11) + (j << 3) + (rr & 7);   // cols 16..31

  // ---- preload B fragments into registers ----
  bf16x8 B0[9], B1[9];
#pragma unroll
  for (int it = 0; it < 8; ++it) {
    int kb = (wid + 8 * (it >> 1)) * 64 + (it & 1) * 32 + kg * 8;
    B0[it] = *(const bf16x8*)(WhT + (size_t)gcol0 * VOCAB + kb);
    B1[it] = *(const bf16x8*)(WhT + (size_t)gcol1 * VOCAB + kb);
  }
  {
    int kbx = wid * 32 + kg * 8;
    B0[8] = *(const bf16x8*)(WxT + (size_t)gcol0 * EMBD + kbx);
    B1[8] = *(const bf16x8*)(WxT + (size_t)gcol1 * EMBD + kbx);
  }

  // ---- epilogue constants; c in registers ----
  const int m = wid >> 1;                  // fragment 0..3
  const int half = wid & 1;                // r in {2*half, 2*half+1}
  const int s_ = (lane >> 3) & 1;
  const int vc = lane & 7;
  const int v = (j << 3) + vc;
  const float bias0 = bias[s_ * 2048 + v];        // frag0 gate: i (s=0) / f (s=1)
  const float bias1 = bias[(2 + s_) * 2048 + v];  // frag1 gate: g (s=0) / o (s=1)
  const int row0 = m * 16 + kg * 4 + half * 2;
  const int row1 = row0 + 1;
  float c_reg[2] = {0.f, 0.f};

  for (int t = 0; t < TLEN; ++t) {
    const int par = t & 1;
    const __hip_bfloat16* hcur = hring + (size_t)t * (BATCH * VOCAB);
    __hip_bfloat16* hnext = (__hip_bfloat16*)hring + (size_t)(t + 1) * (BATCH * VOCAB);
    const int tnext = (t + 1 < TLEN) ? t + 1 : TLEN - 1;
    const int tok0 = tokens[row0 * TLEN + tnext];
    const int tok1 = tokens[row1 * TLEN + tnext];

    // ---- bounds value for step t -> sval[t] (wave 0 of blocks j<64) ----
    if (j < BATCH && wid == 0) {
      float val;
      if (t == 0) {
        int tok = tokens[j * TLEN];
        val = 1.5f * (2.f * tok + 1.f) * (1.f / 2048.f);
      } else {
        const float* st = stats + par * 3 * BATCH * NBLK;
        float2 u0a = load_agent_f32x2(st + (0 * BATCH + j) * NBLK + lane * 4);
        float2 u0b = load_agent_f32x2(st + (0 * BATCH + j) * NBLK + lane * 4 + 2);
        float2 u1a = load_agent_f32x2(st + (1 * BATCH + j) * NBLK + lane * 4);
        float2 u1b = load_agent_f32x2(st + (1 * BATCH + j) * NBLK + lane * 4 + 2);
        float2 u2a = load_agent_f32x2(st + (2 * BATCH + j) * NBLK + lane * 4);
        float2 u2b = load_agent_f32x2(st + (2 * BATCH + j) * NBLK + lane * 4 + 2);
        float a0 = u0a.x + u0a.y + u0b.x + u0b.y;
        float a1 = u1a.x + u1a.y + u1b.x + u1b.y;
        float a2 = u2a.x + u2a.y + u2b.x + u2b.y;
#pragma unroll
        for (int mm = 1; mm <= 32; mm <<= 1) {
          a0 += __shfl_xor(a0, mm);
          a1 += __shfl_xor(a1, mm);
          a2 += __shfl_xor(a2, mm);
        }
        val = 1.5f * (2.f * a1 + a2) / a0;
      }
      if (lane == t) sval[t] = val;
    }

    // ---- GEMM: z[64 x 32cols] over K=2304, 8 waves split K, B in regs ----
    f32x4 acc[4][2];
#pragma unroll
    for (int mf = 0; mf < 4; ++mf)
#pragma unroll
      for (int nf = 0; nf < 2; ++nf) acc[mf][nf] = (f32x4){0.f, 0.f, 0.f, 0.f};

    bf16x8 Ar[5][4];
    auto issue = [&](int it) {
      int slot = it % 5;
      if (it < 8) {
        int kb = (wid + 8 * (it >> 1)) * 64 + (it & 1) * 32 + kg * 8;
        const __hip_bfloat16* p = hcur + kb;
        Ar[slot][0] = *(const bf16x8*)(p + (0 * 16 + rr) * VOCAB);
        Ar[slot][1] = *(const bf16x8*)(p + (1 * 16 + rr) * VOCAB);
        Ar[slot][2] = *(const bf16x8*)(p + (2 * 16 + rr) * VOCAB);
        Ar[slot][3] = *(const bf16x8*)(p + (3 * 16 + rr) * VOCAB);
      } else {
        int kbx = wid * 32 + kg * 8;
        const __hip_bfloat16* p = xb + (size_t)t * BATCH * EMBD + kbx;
        Ar[slot][0] = *(const bf16x8*)(p + (0 * 16 + rr) * EMBD);
        Ar[slot][1] = *(const bf16x8*)(p + (1 * 16 + rr) * EMBD);
        Ar[slot][2] = *(const bf16x8*)(p + (2 * 16 + rr) * EMBD);
        Ar[slot][3] = *(const bf16x8*)(p + (3 * 16 + rr) * EMBD);
      }
    };

#pragma unroll
    for (int it = 0; it < 5; ++it) issue(it);
#pragma unroll
    for (int it = 0; it < 9; ++it) {
      const int sl = it % 5;
      acc[0][0] = __builtin_amdgcn_mfma_f32_16x16x32_bf16(Ar[sl][0], B0[it], acc[0][0], 0, 0, 0);
      acc[0][1] = __builtin_amdgcn_mfma_f32_16x16x32_bf16(Ar[sl][0], B1[it], acc[0][1], 0, 0, 0);
      acc[1][0] = __builtin_amdgcn_mfma_f32_16x16x32_bf16(Ar[sl][1], B0[it], acc[1][0], 0, 0, 0);
      acc[1][1] = __builtin_amdgcn_mfma_f32_16x16x32_bf16(Ar[sl][1], B1[it], acc[1][1], 0, 0, 0);
      acc[2][0] = __builtin_amdgcn_mfma_f32_16x16x32_bf16(Ar[sl][2], B0[it], acc[2][0], 0, 0, 0);
      acc[2][1] = __builtin_amdgcn_mfma_f32_16x16x32_bf16(Ar[sl][2], B1[it], acc[2][1], 0, 0, 0);
      acc[3][0] = __builtin_amdgcn_mfma_f32_16x16x32_bf16(Ar[sl][3], B0[it], acc[3][0], 0, 0, 0);
      acc[3][1] = __builtin_amdgcn_mfma_f32_16x16x32_bf16(Ar[sl][3], B1[it], acc[3][1], 0, 0, 0);
      if (it + 5 < 9) issue(it + 5);
    }

    // ---- cross-wave K reduction ----
#pragma unroll
    for (int mf = 0; mf < 4; ++mf)
#pragma unroll
      for (int nf = 0; nf < 2; ++nf)
#pragma unroll
        for (int r = 0; r < 4; ++r) racc[wid][mf][nf][r][lane] = acc[mf][nf][r];
    __syncthreads();

    // ---- epilogue: wave pair (2m,2m+1) finishes fragment m; half splits r ----
    float hn_[2], e_[2], sl_[2], st_[2];
#pragma unroll
    for (int r2 = 0; r2 < 2; ++r2) {
      int r = half * 2 + r2;
      float z0 = bias0, z1 = bias1;
#pragma unroll
      for (int w = 0; w < 8; ++w) {
        z0 += racc[w][m][0][r][lane];
        z1 += racc[w][m][1][r][lane];
      }
      float o0 = __shfl_xor(z0, 8);
      float o1 = __shfl_xor(z1, 8);
      float zi = s_ ? o0 : z0;
      float zf = s_ ? z0 : o0;
      float zg = s_ ? o1 : z1;
      float zo = s_ ? z1 : o1;
      float gi = 1.f / (1.f + __expf(-zi));
      float gf = 1.f / (1.f + __expf(-zf));
      float go = 1.f / (1.f + __expf(-zo));
      float cnew = gf * c_reg[r2] + gi * tanhf(zg);
      float hn = go * tanhf(cnew);
      c_reg[r2] = cnew;
      hn_[r2] = hn;
      float e = __expf(hn);
      int tok = r2 ? tok1 : tok0;
      e_[r2] = e;
      sl_[r2] = (v < tok) ? e : 0.f;
      st_[r2] = (v == tok) ? e : 0.f;
    }

    // h-slice: pack vc pairs -> 4B agent-scope stores (bypass L2 -> LLC)
    {
      unsigned b0 = bf16_bits(hn_[0]), b1 = bf16_bits(hn_[1]);
      unsigned q0 = (unsigned)__shfl_xor((int)b0, 1);
      unsigned q1 = (unsigned)__shfl_xor((int)b1, 1);
      if (!s_ && !(vc & 1)) {
        store_agent_u32((unsigned*)(hnext + row0 * VOCAB + v), b0 | (q0 << 16));
        store_agent_u32((unsigned*)(hnext + row1 * VOCAB + v), b1 | (q1 << 16));
      }
    }
#pragma unroll
    for (int mm = 1; mm <= 4; mm <<= 1)
#pragma unroll
      for (int r2 = 0; r2 < 2; ++r2) {
        e_[r2] += __shfl_xor(e_[r2], mm);
        sl_[r2] += __shfl_xor(sl_[r2], mm);
        st_[r2] += __shfl_xor(st_[r2], mm);
      }
    if (vc == 0 && s_ == 0) {
      float* stn = stats + (par ^ 1) * 3 * BATCH * NBLK;
      store_agent_f32(&stn[(0 * BATCH + row0) * NBLK + j], e_[0]);
      store_agent_f32(&stn[(1 * BATCH + row0) * NBLK + j], sl_[0]);
      store_agent_f32(&stn[(2 * BATCH + row0) * NBLK + j], st_[0]);
      store_agent_f32(&stn[(0 * BATCH + row1) * NBLK + j], e_[1]);
      store_agent_f32(&stn[(1 * BATCH + row1) * NBLK + j], sl_[1]);
      store_agent_f32(&stn[(2 * BATCH + row1) * NBLK + j], st_[1]);
    }

    if (t < TLEN - 1) grid_barrier(bar, t, j);
  }

  // ---- write out[j] once: d<=t' -> sval[d], else 1.5 (initial bounds) ----
  if (j < BATCH) {
    __syncthreads();
    for (int idx = tid; idx < TLEN * LATD; idx += 512) {
      int tp = idx >> 6, d = idx & 63;
      out[j * TLEN * LATD + idx] = (d < TLEN && d <= tp) ? sval[d] : 1.5f;
    }
  }
}

extern "C" void kernel_launch(void* const* d_in, const int* in_sizes, int n_in,
                              void* d_out, int out_size, void* d_ws, size_t ws_size,
                              hipStream_t stream) {
  (void)in_sizes; (void)n_in; (void)out_size; (void)ws_size;
  const int* tokens = (const int*)d_in[0];
  const float* emb  = (const float*)d_in[1];
  const float* Wx   = (const float*)d_in[2];
  const float* Wh   = (const float*)d_in[3];
  const float* bias = (const float*)d_in[4];
  float* out = (float*)d_out;
  char* ws = (char*)d_ws;

  __hip_bfloat16* WhT = (__hip_bfloat16*)(ws);               // 33,554,432 B
  __hip_bfloat16* WxT = (__hip_bfloat16*)(ws + 33554432);    //  4,194,304 B
  __hip_bfloat16* xb  = (__hip_bfloat16*)(ws + 37748736);    //  1,048,576 B
  __hip_bfloat16* hr  = (__hip_bfloat16*)(ws + 38797312);    //  8,650,752 B (33 slots)
  float* stats        = (float*)(ws + 47448064);             //    393,216 B
  unsigned* bar       = (unsigned*)(ws + 47841280);          //     18,944 B

  k_init<<<512, 256, 0, stream>>>((ushort*)hr, bar);
  k_transpose<<<4096, 256, 0, stream>>>(Wh, WhT, 2048);
  k_transpose<<<512, 256, 0, stream>>>(Wx, WxT, 256);
  k_gather<<<512, 256, 0, stream>>>(tokens, emb, xb);
  k_persist<<<NBLK, 512, 0, stream>>>(tokens, WhT, WxT, xb, bias, hr, stats, out, bar);
}

// Round 7
// 255.300 us; speedup vs baseline: 2.1325x; 1.6084x over previous
//
#include <hip/hip_runtime.h>
#include <hip/hip_bf16.h>

#define VOCAB 2048
#define EMBD  256
#define LATD  64
#define TLEN  32
#define BATCH 64
#define NBLK  256
#define NCG   128   // column groups (16 vocab cols each); rows split 2-way

typedef __attribute__((ext_vector_type(8))) short bf16x8;
typedef __attribute__((ext_vector_type(4))) float f32x4;

// ---------------- init: h ring slot0 = 0, arrv/rel = 0 ----------------
__global__ void k_init(ushort* __restrict__ h0, unsigned* __restrict__ arrv) {
  int i = blockIdx.x * 256 + threadIdx.x;   // grid 512*256 = 131072
  h0[i] = 0;                                 // 64*2048 bf16 (ring slot 0)
  if (i < 384) arrv[i] = 0;                  // 256 arrv + 128 rel words
}

// ---------- transpose+convert: src[K][8192] f32 -> dst[8192][K] bf16 ----------
__global__ void k_transpose(const float* __restrict__ src,
                            __hip_bfloat16* __restrict__ dst, int K) {
  __shared__ __hip_bfloat16 tile[64][72];
  int k0 = (blockIdx.x >> 7) * 64;
  int n0 = (blockIdx.x & 127) * 64;
  int tid = threadIdx.x;
  {
    int kl = tid >> 2;
    int nq = (tid & 3) << 4;
    const float* s = src + (size_t)(k0 + kl) * 8192 + n0 + nq;
#pragma unroll
    for (int i = 0; i < 4; ++i) {
      float4 v = *reinterpret_cast<const float4*>(s + i * 4);
      tile[nq + i * 4 + 0][kl] = __float2bfloat16(v.x);
      tile[nq + i * 4 + 1][kl] = __float2bfloat16(v.y);
      tile[nq + i * 4 + 2][kl] = __float2bfloat16(v.z);
      tile[nq + i * 4 + 3][kl] = __float2bfloat16(v.w);
    }
  }
  __syncthreads();
  {
    int nl = tid >> 2;
    int kq = (tid & 3) << 4;
    uint4* d = reinterpret_cast<uint4*>(dst + (size_t)(n0 + nl) * K + k0 + kq);
    const uint4* s = reinterpret_cast<const uint4*>(&tile[nl][kq]);
    d[0] = s[0];
    d[1] = s[1];
  }
}

// ---------- gather: xb[t*64+b][256] = bf16(emb[tokens[b][t]]) ----------
__global__ void k_gather(const int* __restrict__ tokens,
                         const float* __restrict__ emb,
                         __hip_bfloat16* __restrict__ xb) {
  int tid = threadIdx.x;
  int row = blockIdx.x * 4 + (tid >> 6);   // 512 blocks -> 2048 rows
  int lane = tid & 63;
  int t = row >> 6, b = row & 63;
  int tok = tokens[b * TLEN + t];
  float4 v = *reinterpret_cast<const float4*>(emb + (size_t)tok * EMBD + lane * 4);
  __hip_bfloat16* d = xb + (size_t)row * EMBD + lane * 4;
  d[0] = __float2bfloat16(v.x);
  d[1] = __float2bfloat16(v.y);
  d[2] = __float2bfloat16(v.z);
  d[3] = __float2bfloat16(v.w);
}

__device__ __forceinline__ void store_agent_u32(unsigned* p, unsigned v) {
  __hip_atomic_store(p, v, __ATOMIC_RELAXED, __HIP_MEMORY_SCOPE_AGENT);
}
__device__ __forceinline__ unsigned load_agent_u32(const unsigned* p) {
  return __hip_atomic_load(p, __ATOMIC_RELAXED, __HIP_MEMORY_SCOPE_AGENT);
}
__device__ __forceinline__ unsigned long long load_agent_u64(const void* p) {
  return __hip_atomic_load((const unsigned long long*)p, __ATOMIC_RELAXED,
                           __HIP_MEMORY_SCOPE_AGENT);
}
__device__ __forceinline__ void store_agent_f32(float* p, float v) {
  __hip_atomic_store(p, v, __ATOMIC_RELAXED, __HIP_MEMORY_SCOPE_AGENT);
}
__device__ __forceinline__ float2 load_agent_f32x2(const float* p) {
  unsigned long long u = load_agent_u64(p);
  float2 f;
  __builtin_memcpy(&f, &u, 8);
  return f;
}
__device__ __forceinline__ unsigned short bf16_bits(float x) {
  __hip_bfloat16 h = __float2bfloat16(x);
  unsigned short u;
  __builtin_memcpy(&u, &h, 2);
  return u;
}

// Store-based grid barrier (no atomic RMW anywhere).
// Arrival: each block STORES t+1 into its own arrv word (parallel at LLC).
// Detection: block 0 wave 0 polls all 256 words (4/lane via two 8B agent
// loads). Release: lanes 0..7 store t+1 to 8 per-XCD release lines.
// Values are monotone (t+1) -> no reset, slots reused across steps.
// Visibility: producers' h/stats agent-stores are drained by the
// __syncthreads (vmcnt 0 before s_barrier) BEFORE the arrival store issues.
__device__ __forceinline__ void grid_barrier(unsigned* arrv, unsigned* rel,
                                             int t, int j, int tid, int lane,
                                             int wid) {
  __syncthreads();                       // all waves' stores drained
  const unsigned want = (unsigned)(t + 1);
  if (j == 0) {
    if (wid == 0) {
      if (lane == 0) store_agent_u32(arrv, want);
      for (;;) {
        unsigned long long a = load_agent_u64(arrv + 2 * lane);
        unsigned long long b = load_agent_u64(arrv + 128 + 2 * lane);
        bool ok = ((unsigned)a >= want) && ((unsigned)(a >> 32) >= want) &&
                  ((unsigned)b >= want) && ((unsigned)(b >> 32) >= want);
        if (__all(ok)) break;
      }
      if (lane < 8) store_agent_u32(rel + (lane << 4), want);
    }
  } else {
    if (tid == 0) {
      store_agent_u32(arrv + j, want);
      while (load_agent_u32(rel + ((j & 7) << 4)) < want)
        __builtin_amdgcn_s_sleep(1);
    }
  }
  __syncthreads();
}

// ---------------- persistent kernel: all 32 steps ----------------
// 256 blocks x 512 threads, 1 block/CU. Block j = (cg, rg): cg = j>>1 owns
// vocab cols cg*16..cg*16+15; rg = j&1 owns batch rows rg*32..rg*32+31.
// Per-block A traffic = 32 rows x 2304 K x 2B = 144 KB/step (was 288).
// 8 waves split K 8-ways; each wave: 2 m-frags x 4 gate-frags x 9 iters.
// Wh/Wx B-fragments in VGPRs for the whole kernel (144 VGPR); c in regs.
__global__ __launch_bounds__(512, 1) void k_persist(
    const int* __restrict__ tokens,
    const __hip_bfloat16* __restrict__ WhT,   // [8192][2048]
    const __hip_bfloat16* __restrict__ WxT,   // [8192][256]
    const __hip_bfloat16* __restrict__ xb,    // [2048][256] row = t*64+b
    const float* __restrict__ bias,           // [8192]
    __hip_bfloat16* __restrict__ hring,       // [33][64][2048]
    float* __restrict__ stats,                // [2][3][64][128]
    float* __restrict__ out,                  // [64][32][64]
    unsigned* __restrict__ arrv,              // [256] + rel after
    unsigned* __restrict__ rel) {             // [8*16]
  const int tid = threadIdx.x;
  const int lane = tid & 63;
  const int wid = tid >> 6;                  // 0..7 = K-split
  const int j = blockIdx.x;
  const int cg = j >> 1;                     // column group 0..127
  const int rg = j & 1;                      // row group 0..1
  const int r0 = rg << 5;                    // first batch row

  __shared__ float racc[8][2][4][4][64];   // [wid][mf][gt][r][lane] 64KB
  __shared__ float sval[TLEN];

  const int rr = lane & 15;
  const int kg = lane >> 4;                 // 0..3 (K groups of 8)

  // ---- preload B fragments into registers (loop-invariant, 144 VGPR) ----
  bf16x8 Bf[9][4];
#pragma unroll
  for (int it = 0; it < 8; ++it) {
    int kb = (wid * 8 + it) * 32 + kg * 8;
#pragma unroll
    for (int gt = 0; gt < 4; ++gt)
      Bf[it][gt] = *(const bf16x8*)(WhT + (size_t)((gt << 11) + (cg << 4) + rr) * VOCAB + kb);
  }
  {
    int kx = wid * 32 + kg * 8;
#pragma unroll
    for (int gt = 0; gt < 4; ++gt)
      Bf[8][gt] = *(const bf16x8*)(WxT + (size_t)((gt << 11) + (cg << 4) + rr) * EMBD + kx);
  }

  // ---- epilogue constants: this thread owns cell (rowg, v) ----
  const int m_e = wid >> 2;                 // 0..1
  const int r_e = wid & 3;                  // 0..3
  const int rowg = r0 + m_e * 16 + kg * 4 + r_e;   // global batch row
  const int v = (cg << 4) + rr;             // global vocab col
  float bias_r[4];
#pragma unroll
  for (int gt = 0; gt < 4; ++gt) bias_r[gt] = bias[gt * 2048 + v];
  float c_reg = 0.f;

  for (int t = 0; t < TLEN; ++t) {
    const int par = t & 1;
    const __hip_bfloat16* hcur = hring + (size_t)t * (BATCH * VOCAB);
    __hip_bfloat16* hnext = (__hip_bfloat16*)hring + (size_t)(t + 1) * (BATCH * VOCAB);
    const int tnext = (t + 1 < TLEN) ? t + 1 : TLEN - 1;
    const int tok = tokens[rowg * TLEN + tnext];

    // ---- bounds value for step t -> sval[t] (wave 0 of blocks j<64) ----
    if (j < BATCH && wid == 0) {
      float val;
      if (t == 0) {
        int tk = tokens[j * TLEN];
        val = 1.5f * (2.f * tk + 1.f) * (1.f / 2048.f);
      } else {
        const float* st = stats + par * 3 * BATCH * NCG;
        float2 u0 = load_agent_f32x2(st + (0 * BATCH + j) * NCG + lane * 2);
        float2 u1 = load_agent_f32x2(st + (1 * BATCH + j) * NCG + lane * 2);
        float2 u2 = load_agent_f32x2(st + (2 * BATCH + j) * NCG + lane * 2);
        float a0 = u0.x + u0.y, a1 = u1.x + u1.y, a2 = u2.x + u2.y;
#pragma unroll
        for (int mm = 1; mm <= 32; mm <<= 1) {
          a0 += __shfl_xor(a0, mm);
          a1 += __shfl_xor(a1, mm);
          a2 += __shfl_xor(a2, mm);
        }
        val = 1.5f * (2.f * a1 + a2) / a0;
      }
      if (lane == t) sval[t] = val;
    }

    // ---- GEMM: z[32 rows x 64 zcols] over K=2304, 8 waves split K ----
    f32x4 acc[2][4];
#pragma unroll
    for (int mf = 0; mf < 2; ++mf)
#pragma unroll
      for (int gt = 0; gt < 4; ++gt) acc[mf][gt] = (f32x4){0.f, 0.f, 0.f, 0.f};

    bf16x8 Ar[2][2];
    auto issue = [&](int it) {
      int slot = it & 1;
      if (it < 8) {
        int kb = (wid * 8 + it) * 32 + kg * 8;
        const __hip_bfloat16* p = hcur + kb;
        Ar[slot][0] = *(const bf16x8*)(p + (r0 + rr) * VOCAB);
        Ar[slot][1] = *(const bf16x8*)(p + (r0 + 16 + rr) * VOCAB);
      } else {
        int kx = wid * 32 + kg * 8;
        const __hip_bfloat16* p = xb + (size_t)t * BATCH * EMBD + kx;
        Ar[slot][0] = *(const bf16x8*)(p + (r0 + rr) * EMBD);
        Ar[slot][1] = *(const bf16x8*)(p + (r0 + 16 + rr) * EMBD);
      }
    };

    issue(0);
#pragma unroll
    for (int it = 0; it < 9; ++it) {
      if (it + 1 < 9) issue(it + 1);
      const int sl = it & 1;
#pragma unroll
      for (int gt = 0; gt < 4; ++gt) {
        acc[0][gt] = __builtin_amdgcn_mfma_f32_16x16x32_bf16(Ar[sl][0], Bf[it][gt], acc[0][gt], 0, 0, 0);
        acc[1][gt] = __builtin_amdgcn_mfma_f32_16x16x32_bf16(Ar[sl][1], Bf[it][gt], acc[1][gt], 0, 0, 0);
      }
    }

    // ---- cross-wave K reduction ----
#pragma unroll
    for (int mf = 0; mf < 2; ++mf)
#pragma unroll
      for (int gt = 0; gt < 4; ++gt)
#pragma unroll
        for (int r = 0; r < 4; ++r) racc[wid][mf][gt][r][lane] = acc[mf][gt][r];
    __syncthreads();

    // ---- epilogue: one cell per thread; all 4 gates from LDS ----
    float z[4];
#pragma unroll
    for (int gt = 0; gt < 4; ++gt) {
      float s = bias_r[gt];
#pragma unroll
      for (int w = 0; w < 8; ++w) s += racc[w][m_e][gt][r_e][lane];
      z[gt] = s;
    }
    float gi = 1.f / (1.f + __expf(-z[0]));
    float gf = 1.f / (1.f + __expf(-z[1]));
    float go = 1.f / (1.f + __expf(-z[3]));
    float cnew = gf * c_reg + gi * tanhf(z[2]);
    float hn = go * tanhf(cnew);
    c_reg = cnew;

    // h store: pack col pairs -> one u32 agent store (LLC) per even lane
    {
      unsigned b0 = bf16_bits(hn);
      unsigned q0 = (unsigned)__shfl_xor((int)b0, 1);
      if (!(rr & 1))
        store_agent_u32((unsigned*)(hnext + rowg * VOCAB + v), b0 | (q0 << 16));
    }

    // stats partials over this block's 16 cols (reduce within 16-lane group)
    float e = __expf(hn);
    float sl = (v < tok) ? e : 0.f;
    float st = (v == tok) ? e : 0.f;
#pragma unroll
    for (int mm = 1; mm <= 8; mm <<= 1) {
      e += __shfl_xor(e, mm);
      sl += __shfl_xor(sl, mm);
      st += __shfl_xor(st, mm);
    }
    if (rr == 0) {
      float* stn = stats + (par ^ 1) * 3 * BATCH * NCG;
      store_agent_f32(&stn[(0 * BATCH + rowg) * NCG + cg], e);
      store_agent_f32(&stn[(1 * BATCH + rowg) * NCG + cg], sl);
      store_agent_f32(&stn[(2 * BATCH + rowg) * NCG + cg], st);
    }

    if (t < TLEN - 1) grid_barrier(arrv, rel, t, j, tid, lane, wid);
  }

  // ---- write out[j] once: d<=t' -> sval[d], else 1.5 (initial bounds) ----
  if (j < BATCH) {
    __syncthreads();
    for (int idx = tid; idx < TLEN * LATD; idx += 512) {
      int tp = idx >> 6, d = idx & 63;
      out[j * TLEN * LATD + idx] = (d < TLEN && d <= tp) ? sval[d] : 1.5f;
    }
  }
}

extern "C" void kernel_launch(void* const* d_in, const int* in_sizes, int n_in,
                              void* d_out, int out_size, void* d_ws, size_t ws_size,
                              hipStream_t stream) {
  (void)in_sizes; (void)n_in; (void)out_size; (void)ws_size;
  const int* tokens = (const int*)d_in[0];
  const float* emb  = (const float*)d_in[1];
  const float* Wx   = (const float*)d_in[2];
  const float* Wh   = (const float*)d_in[3];
  const float* bias = (const float*)d_in[4];
  float* out = (float*)d_out;
  char* ws = (char*)d_ws;

  __hip_bfloat16* WhT = (__hip_bfloat16*)(ws);               // 33,554,432 B
  __hip_bfloat16* WxT = (__hip_bfloat16*)(ws + 33554432);    //  4,194,304 B
  __hip_bfloat16* xb  = (__hip_bfloat16*)(ws + 37748736);    //  1,048,576 B
  __hip_bfloat16* hr  = (__hip_bfloat16*)(ws + 38797312);    //  8,650,752 B (33 slots)
  float* stats        = (float*)(ws + 47448064);             //    196,608 B
  unsigned* arrv      = (unsigned*)(ws + 47644672);          //      1,024 B
  unsigned* rel       = (unsigned*)(ws + 47645696);          //        512 B

  k_init<<<512, 256, 0, stream>>>((ushort*)hr, arrv);
  k_transpose<<<4096, 256, 0, stream>>>(Wh, WhT, 2048);
  k_transpose<<<512, 256, 0, stream>>>(Wx, WxT, 256);
  k_gather<<<512, 256, 0, stream>>>(tokens, emb, xb);
  k_persist<<<NBLK, 512, 0, stream>>>(tokens, WhT, WxT, xb, bias, hr, stats, out, arrv, rel);
}